// Round 7
// baseline (171.048 us; speedup 1.0000x reference)
//
#include <hip/hip_runtime.h>
#include <hip/hip_bf16.h>

// FullAttention: N=2, L=S=2048, H=16, E=D=64, fp32 in/out, additive mask.
// R7: q=32/wave (halves per-q LDS fragment traffic - the LDS-BW floor),
// split-S=2 keeps grid=1024 (4 blocks/CU at 40KB LDS). Mask global->reg,
// added after QK (C=0). Ps sequenced per-cb in 8KB. Combine kernel sums
// split partials (plain sums - no online max) and normalizes.

typedef short bf16x8 __attribute__((ext_vector_type(8)));
typedef short short4v __attribute__((ext_vector_type(4)));
typedef unsigned uint2v __attribute__((ext_vector_type(2)));
typedef float f32x4 __attribute__((ext_vector_type(4)));

constexpr int Nb = 2, Lq = 2048, Sk = 2048, Hh = 16, Ee = 64, Dd = 64;
constexpr int BM = 128;     // Q rows per block (4 waves x 32)
constexpr int BN = 64;      // K/V rows per S-tile
constexpr int NT = Sk / BN; // 32 tiles
constexpr int KVB = Nb * Hh * NT * 16 * 64 / 256;  // 8192 prep blocks for KV
constexpr float SCALE_LOG2E = 0.125f * 1.4426950408889634f;  // (1/sqrt(64)) * log2(e)

__device__ __forceinline__ short f2bf(float f) {
  union { float f; unsigned u; } v; v.f = f;
  unsigned r = (v.u + 0x7fffu + ((v.u >> 16) & 1u)) >> 16;  // RNE
  return (short)r;
}

__device__ __forceinline__ unsigned pack_bf16x2(float a, float b) {
  union { __hip_bfloat162 h; unsigned u; } v;
  float2 f; f.x = a; f.y = b;
  v.h = __float22bfloat162_rn(f);
  return v.u;
}

__device__ __forceinline__ float bf_lo(unsigned u) { return __uint_as_float(u << 16); }
__device__ __forceinline__ float bf_hi(unsigned u) { return __uint_as_float(u & 0xffff0000u); }

__device__ __forceinline__ void async_copy16(const void* g, void* l) {
  __builtin_amdgcn_global_load_lds(
      (const __attribute__((address_space(1))) unsigned int*)g,
      (__attribute__((address_space(3))) unsigned int*)l, 16, 0, 0);
}

// Blocks [0, KVB): K and V^T into MFMA-fragment order (unchanged).
// Blocks [KVB, KVB+4096): mask -> bf16*SCALE_LOG2E in fragment order for
// BM=128: [qt(16)][w(4)][cb(2)][t(32)][sb(4)][lane(64): 4 shorts].
__global__ __launch_bounds__(256) void prep_all(const float* __restrict__ K,
                                                const float* __restrict__ V,
                                                const float* __restrict__ M,
                                                short* __restrict__ KVf,
                                                short* __restrict__ Mg) {
  if (blockIdx.x < KVB) {
    int gid = blockIdx.x * 256 + threadIdx.x;
    int l = gid & 63;
    int chunkid = gid >> 6;
    int ch = chunkid & 15;
    int t  = (chunkid >> 4) & 31;
    int nh = chunkid >> 9;
    int n = nh >> 4, h = nh & 15;
    int c = l & 15, quad = l >> 4;
    bf16x8 o;
    if (ch < 8) {
      int sb = ch >> 1, kc = ch & 1;
      int s = t * 64 + sb * 16 + c;
      int e0 = kc * 32 + quad * 8;
      const float* p = K + (((size_t)n * Sk + s) * Hh + h) * Ee + e0;
      float4 x = *(const float4*)(p);
      float4 y = *(const float4*)(p + 4);
      o[0] = f2bf(x.x); o[1] = f2bf(x.y); o[2] = f2bf(x.z); o[3] = f2bf(x.w);
      o[4] = f2bf(y.x); o[5] = f2bf(y.y); o[6] = f2bf(y.z); o[7] = f2bf(y.w);
    } else {
      int db = (ch - 8) >> 1, kc = (ch - 8) & 1;
      int d = db * 16 + c;
      int s0 = t * 64 + kc * 32 + quad * 8;
      const float* p = V + (((size_t)n * Sk + s0) * Hh + h) * Dd + d;
#pragma unroll
      for (int j = 0; j < 8; ++j) o[j] = f2bf(p[(size_t)j * Hh * Dd]);
    }
    *(bf16x8*)(KVf + (size_t)gid * 8) = o;
  } else {
    int u = (blockIdx.x - KVB) * 256 + threadIdx.x;  // one 4-elem granule
    int colg = u & 511;          // granule along the 2048-col mask row
    int row  = u >> 9;           // global q row
    int qt = row >> 7, wv = (row >> 5) & 3, cb = (row >> 4) & 1, cc = row & 15;
    int t = colg >> 4, sb = (colg >> 2) & 3, quad = colg & 3;
    int lane = quad * 16 + cc;
    float4 mv = *(const float4*)(M + (size_t)row * Sk + colg * 4);
    short4v o;
    o[0] = f2bf(mv.x * SCALE_LOG2E); o[1] = f2bf(mv.y * SCALE_LOG2E);
    o[2] = f2bf(mv.z * SCALE_LOG2E); o[3] = f2bf(mv.w * SCALE_LOG2E);
    size_t gran = ((((size_t)((qt * 4 + wv) * 2 + cb) * 32 + t) * 4 + sb) * 64) + lane;
    *(short4v*)(Mg + gran * 4) = o;
  }
}

template <int NS>
__global__ __launch_bounds__(256, 4) void attn_fwd(
    const float* __restrict__ Q, const short* __restrict__ KVf,
    const short* __restrict__ Mg, float* __restrict__ P0,
    float* __restrict__ P1, float* __restrict__ rsW)
{
  __shared__ short KV[2][8192];   // K+V^T fragment chunks, double-buffered (2x16KB)
  __shared__ short Ps[4][1024];   // per-wave P^T, 16 rows x 64, XOR-swizzled (8KB)

  const int tid  = threadIdx.x;
  const int lane = tid & 63;
  const int w    = tid >> 6;     // wave 0..3
  const int quad = lane >> 4;    // 0..3
  const int c    = lane & 15;    // 0..15

  // XCD-aware decode: XCD (id&7) hosts 4 nh values -> KV set 2.1MB fits L2.
  const int id   = blockIdx.x;
  const int slot = id >> 3;
  const int nh   = (id & 7) * 4 + (slot & 3);
  const int qt   = (slot >> 2) & 15;
  const int sp   = (NS == 2) ? (slot >> 6) : 0;
  const int n    = nh >> 4;
  const int h    = nh & 15;

  const int row0 = qt * BM + w * 32;   // wave's first global q row
  const int t0 = sp * (NT / NS), tc = NT / NS;

  // ---- Q fragments, pre-scaled (B-operand layout), 2 q-rows per lane ----
  bf16x8 qfrag[2][2];   // [cb][kc]
#pragma unroll
  for (int cb = 0; cb < 2; ++cb) {
    const float* qp = Q + (((size_t)n * Lq + (row0 + cb * 16 + c)) * Hh + h) * Ee;
#pragma unroll
    for (int kc = 0; kc < 2; ++kc) {
      const float* p = qp + kc * 32 + quad * 8;
      float4 x = *(const float4*)(p);
      float4 y = *(const float4*)(p + 4);
      bf16x8 f;
      f[0] = f2bf(x.x * SCALE_LOG2E); f[1] = f2bf(x.y * SCALE_LOG2E);
      f[2] = f2bf(x.z * SCALE_LOG2E); f[3] = f2bf(x.w * SCALE_LOG2E);
      f[4] = f2bf(y.x * SCALE_LOG2E); f[5] = f2bf(y.y * SCALE_LOG2E);
      f[6] = f2bf(y.z * SCALE_LOG2E); f[7] = f2bf(y.w * SCALE_LOG2E);
      qfrag[cb][kc] = f;
    }
  }

  f32x4 o[2][4];
#pragma unroll
  for (int cb = 0; cb < 2; ++cb)
#pragma unroll
    for (int db = 0; db < 4; ++db) { o[cb][db][0] = 0.f; o[cb][db][1] = 0.f; o[cb][db][2] = 0.f; o[cb][db][3] = 0.f; }
  float rs[2] = {0.f, 0.f};

  const short* kvt = KVf + (size_t)nh * NT * 8192;
  // mask stream: [ (qt*4+w)*2+cb ][t][sb][lane]*4 shorts
  const short* mbase = Mg + (size_t)((qt * 4 + w) * 2) * 32768 + lane * 4;

  // ---- prologue: async-stage KV tile t0 ----
#pragma unroll
  for (int i = 0; i < 4; ++i) {
    int ch = w * 4 + i;
    async_copy16(kvt + ((size_t)t0 * 8192) + ch * 512 + lane * 8, &KV[0][ch * 512 + lane * 8]);
  }
  __syncthreads();

  for (int tt = 0; tt < tc; ++tt) {
    const int t = t0 + tt;
    const int buf = tt & 1;

    // ---- mask loads for current tile (issued BEFORE async so the mask
    //      consume waits vmcnt(4), keeping the KV prefetch in flight) ----
    uint2v mv[2][4];
#pragma unroll
    for (int cb = 0; cb < 2; ++cb)
#pragma unroll
      for (int sb = 0; sb < 4; ++sb)
        mv[cb][sb] = *(const uint2v*)(mbase + ((size_t)cb * 32 + t) * 1024 + sb * 256);

    // ---- issue async KV loads for tile t+1 ----
    if (tt + 1 < tc) {
      const short* gk = kvt + (size_t)(t + 1) * 8192;
#pragma unroll
      for (int i = 0; i < 4; ++i) {
        int ch = w * 4 + i;
        async_copy16(gk + ch * 512 + lane * 8, &KV[buf ^ 1][ch * 512 + lane * 8]);
      }
    }

    const short* kb = &KV[buf][0];

    // ---- S^T = K Q^T with C=0; mask added after ----
    f32x4 sacc[2][4];
#pragma unroll
    for (int cb = 0; cb < 2; ++cb)
#pragma unroll
      for (int sb = 0; sb < 4; ++sb) { sacc[cb][sb][0] = 0.f; sacc[cb][sb][1] = 0.f; sacc[cb][sb][2] = 0.f; sacc[cb][sb][3] = 0.f; }
#pragma unroll
    for (int kc = 0; kc < 2; ++kc) {
#pragma unroll
      for (int sb = 0; sb < 4; ++sb) {
        bf16x8 kfrag = *(const bf16x8*)&kb[(sb * 2 + kc) * 512 + lane * 8];
#pragma unroll
        for (int cb = 0; cb < 2; ++cb)
          sacc[cb][sb] = __builtin_amdgcn_mfma_f32_16x16x32_bf16(kfrag, qfrag[cb][kc], sacc[cb][sb], 0, 0, 0);
      }
    }

    // ---- add mask, exp2, accumulate rs, pack, P^T via 8KB Ps (cb-sequenced) ----
    bf16x8 pfrag[2][2];   // [cb][kc]
#pragma unroll
    for (int cb = 0; cb < 2; ++cb) {
#pragma unroll
      for (int sb = 0; sb < 4; ++sb) {
        float p0 = __builtin_amdgcn_exp2f(sacc[cb][sb][0] + bf_lo(mv[cb][sb].x));
        float p1 = __builtin_amdgcn_exp2f(sacc[cb][sb][1] + bf_hi(mv[cb][sb].x));
        float p2 = __builtin_amdgcn_exp2f(sacc[cb][sb][2] + bf_lo(mv[cb][sb].y));
        float p3 = __builtin_amdgcn_exp2f(sacc[cb][sb][3] + bf_hi(mv[cb][sb].y));
        rs[cb] += (p0 + p1) + (p2 + p3);
        uint2v pv;
        pv.x = pack_bf16x2(p0, p1);
        pv.y = pack_bf16x2(p2, p3);
        int gp = ((4 * sb + quad) ^ c) * 4;
        *(uint2v*)&Ps[w][c * 64 + gp] = pv;
      }
#pragma unroll
      for (int kc = 0; kc < 2; ++kc) {
        int G0 = 8 * kc + 2 * quad;
        int ga = (G0 ^ c) * 4, gb = ((G0 + 1) ^ c) * 4;
        union { uint2v u[2]; bf16x8 f; } uu;
        uu.u[0] = *(const uint2v*)&Ps[w][c * 64 + ga];
        uu.u[1] = *(const uint2v*)&Ps[w][c * 64 + gb];
        pfrag[cb][kc] = uu.f;
      }
    }

    // ---- O^T += V^T P^T (vfrag read once, reused across cb) ----
#pragma unroll
    for (int kc = 0; kc < 2; ++kc) {
#pragma unroll
      for (int db = 0; db < 4; ++db) {
        bf16x8 vfrag = *(const bf16x8*)&kb[(8 + db * 2 + kc) * 512 + lane * 8];
#pragma unroll
        for (int cb = 0; cb < 2; ++cb)
          o[cb][db] = __builtin_amdgcn_mfma_f32_16x16x32_bf16(vfrag, pfrag[cb][kc], o[cb][db], 0, 0, 0);
      }
    }

    __syncthreads();  // drains async t+1; protects buf reuse
  }

  // ---- epilogue: write RAW partial O and partial row-sums ----
  float* P = (sp == 0) ? P0 : P1;
#pragma unroll
  for (int cb = 0; cb < 2; ++cb) {
    float v = rs[cb];
    v += __shfl_xor(v, 16, 64);
    v += __shfl_xor(v, 32, 64);
    const int qrow = row0 + cb * 16 + c;
    if (quad == 0) rsW[(size_t)sp * 65536 + nh * 2048 + qrow] = v;
    float* op = P + (((size_t)n * Lq + qrow) * Hh + h) * Dd + quad * 4;
#pragma unroll
    for (int db = 0; db < 4; ++db) {
      float4 ov;
      ov.x = o[cb][db][0]; ov.y = o[cb][db][1];
      ov.z = o[cb][db][2]; ov.w = o[cb][db][3];
      *(float4*)(op + db * 16) = ov;
    }
  }
}

template <int NS>
__global__ __launch_bounds__(256) void combine(float* __restrict__ Out,
                                               const float* __restrict__ P1,
                                               const float* __restrict__ rsW) {
  int gid = blockIdx.x * 256 + threadIdx.x;
  size_t i4 = (size_t)gid * 4;
  int hh = (int)((i4 >> 6) & 15);
  int l  = (int)((i4 >> 10) & 2047);
  int nn = (int)(i4 >> 21);
  int nh = nn * 16 + hh;
  float rs = rsW[nh * 2048 + l];
  float4 v = *(const float4*)(Out + i4);
  if (NS == 2) {
    rs += rsW[65536 + (size_t)nh * 2048 + l];
    float4 b = *(const float4*)(P1 + i4);
    v.x += b.x; v.y += b.y; v.z += b.z; v.w += b.w;
  }
  float inv = 1.0f / rs;
  v.x *= inv; v.y *= inv; v.z *= inv; v.w *= inv;
  *(float4*)(Out + i4) = v;
}

extern "C" void kernel_launch(void* const* d_in, const int* in_sizes, int n_in,
                              void* d_out, int out_size, void* d_ws, size_t ws_size,
                              hipStream_t stream) {
  const float* Q   = (const float*)d_in[0];
  const float* K   = (const float*)d_in[1];
  const float* V   = (const float*)d_in[2];
  const float* Msk = (const float*)d_in[3];
  float* Out = (float*)d_out;

  short* KVf = (short*)d_ws;                         // 16.78 MB
  short* Mg  = KVf + (size_t)8388608;                // 8.39 MB
  float* rsW = (float*)(Mg + (size_t)4194304);       // 0.52 MB (2 splits)
  float* P1  = rsW + 131072;                         // 16.78 MB (split=2 only)

  const size_t need2 = 16777216u + 8388608u + 524288u + 16777216u;
  const bool split = ws_size >= need2;

  prep_all<<<dim3(KVB + 4096), dim3(256), 0, stream>>>(K, V, Msk, KVf, Mg);

  if (split) {
    attn_fwd<2><<<dim3(1024), dim3(256), 0, stream>>>(Q, KVf, Mg, Out, P1, rsW);
    combine<2><<<dim3(4096), dim3(256), 0, stream>>>(Out, P1, rsW);
  } else {
    attn_fwd<1><<<dim3(512), dim3(256), 0, stream>>>(Q, KVf, Mg, Out, P1, rsW);
    combine<1><<<dim3(4096), dim3(256), 0, stream>>>(Out, P1, rsW);
  }
}

// Round 8
// 166.333 us; speedup vs baseline: 1.0283x; 1.0283x over previous
//
#include <hip/hip_runtime.h>
#include <hip/hip_bf16.h>

// FullAttention: N=2, L=S=2048, H=16, E=D=64, fp32 in/out, additive mask.
// R8: PV via mfma_f32_16x16x16bf16_1k whose B-layout (k=4*quad+j) equals the
// QK C/D layout (s=4*quad+r) -> P feeds PV straight from registers, no LDS
// round-trip. V pre-swizzled to the x16 A-layout. Mask lane-contiguous 64B,
// prefetched 1 tile ahead, consumed as C-init. LDS = 32KB (KV dbuf only).

typedef short bf16x8 __attribute__((ext_vector_type(8)));
typedef short short4v __attribute__((ext_vector_type(4)));
typedef unsigned uint2v __attribute__((ext_vector_type(2)));
typedef unsigned uint4v __attribute__((ext_vector_type(4)));
typedef float f32x4 __attribute__((ext_vector_type(4)));

constexpr int Nb = 2, Lq = 2048, Sk = 2048, Hh = 16, Ee = 64, Dd = 64;
constexpr int BM = 128;     // Q rows per block (4 waves x 32)
constexpr int BN = 64;      // K/V rows per S-tile
constexpr int NT = Sk / BN; // 32 tiles
constexpr int KVB = 4096;   // KV prep blocks (1,048,576 threads x 8 shorts)
constexpr int MSKB = 2048;  // mask prep blocks (524,288 threads x 8 shorts)
constexpr float SCALE_LOG2E = 0.125f * 1.4426950408889634f;  // (1/sqrt(64)) * log2(e)

__device__ __forceinline__ short f2bf(float f) {
  union { float f; unsigned u; } v; v.f = f;
  unsigned r = (v.u + 0x7fffu + ((v.u >> 16) & 1u)) >> 16;  // RNE
  return (short)r;
}

__device__ __forceinline__ unsigned pack_bf16x2(float a, float b) {
  union { __hip_bfloat162 h; unsigned u; } v;
  float2 f; f.x = a; f.y = b;
  v.h = __float22bfloat162_rn(f);
  return v.u;
}

__device__ __forceinline__ float bf_lo(unsigned u) { return __uint_as_float(u << 16); }
__device__ __forceinline__ float bf_hi(unsigned u) { return __uint_as_float(u & 0xffff0000u); }

__device__ __forceinline__ void async_copy16(const void* g, void* l) {
  __builtin_amdgcn_global_load_lds(
      (const __attribute__((address_space(1))) unsigned int*)g,
      (__attribute__((address_space(3))) unsigned int*)l, 16, 0, 0);
}

// KV tile layout (8192 shorts = 16KB):
//   [0,4096): K chunks (sb,kc) of 512 shorts: lane l (c=l&15,quad=l>>4) holds
//             K[s=16sb+c][e=32kc+8quad+j], j=0..7  (x32 A-frag, b128 reads)
//   [4096,8192): V chunks (db,sb) of 256 shorts: lane l holds
//             V^T[d=16db+c][s=16sb+4quad+j], j=0..3 (x16 A-frag, b64 reads)
__global__ __launch_bounds__(256) void prep_all(const float* __restrict__ K,
                                                const float* __restrict__ V,
                                                const float* __restrict__ M,
                                                short* __restrict__ KVf,
                                                short* __restrict__ Mg) {
  if (blockIdx.x < KVB) {
    int gid = blockIdx.x * 256 + threadIdx.x;  // 8-short unit index
    int off8 = gid & 1023;                     // unit within 8192-short tile
    int t  = (gid >> 10) & 31;
    int nh = gid >> 15;
    int n = nh >> 4, h = nh & 15;
    short* dst = KVf + ((size_t)(nh * NT + t)) * 8192 + off8 * 8;
    if (off8 < 512) {             // K region
      int ch = off8 >> 6;         // chunk 0..7: sb=ch>>1, kc=ch&1
      int l  = off8 & 63;
      int sb = ch >> 1, kc = ch & 1, c = l & 15, quad = l >> 4;
      const float* p = K + (((size_t)n * Sk + (t * 64 + sb * 16 + c)) * Hh + h) * Ee
                         + kc * 32 + quad * 8;
      float4 x = *(const float4*)(p);
      float4 y = *(const float4*)(p + 4);
      bf16x8 o;
      o[0] = f2bf(x.x); o[1] = f2bf(x.y); o[2] = f2bf(x.z); o[3] = f2bf(x.w);
      o[4] = f2bf(y.x); o[5] = f2bf(y.y); o[6] = f2bf(y.z); o[7] = f2bf(y.w);
      *(bf16x8*)dst = o;
    } else {                      // V region
      int pos = off8 - 512;
      int vch = pos >> 5;         // chunk 0..15: db=vch>>2, sb=vch&3
      int l0  = (pos & 31) * 2;   // this thread covers lanes l0, l0+1
      int db = vch >> 2, sb = vch & 3;
      bf16x8 o;
#pragma unroll
      for (int i = 0; i < 2; ++i) {
        int l = l0 + i, c = l & 15, quad = l >> 4;
        const float* p = V + (((size_t)n * Sk + (t * 64 + sb * 16 + quad * 4)) * Hh + h) * Dd
                           + db * 16 + c;
#pragma unroll
        for (int j = 0; j < 4; ++j) o[i * 4 + j] = f2bf(p[(size_t)j * Hh * Dd]);
      }
      *(bf16x8*)dst = o;
    }
  } else {
    // Mask -> bf16*SCALE_LOG2E, lane-contiguous fragment order:
    // short idx = ((((qt*4+w)*32+t)*64+lane)*4 + (cb*2+sbp))*8
    // unit (8 shorts) = [sb=2sbp: r0..r3][sb=2sbp+1: r0..r3]
    int u = (blockIdx.x - KVB) * 256 + threadIdx.x;   // 0..524287
    int sub  = u & 3;            // cb*2 + sbp
    int lane = (u >> 2) & 63;
    int t    = (u >> 8) & 31;
    int qw   = u >> 13;          // qt*4 + w
    int cb = sub >> 1, sbp = sub & 1;
    int c = lane & 15, quad = lane >> 4;
    int row = (qw >> 2) * 128 + (qw & 3) * 32 + cb * 16 + c;
    short o[8];
#pragma unroll
    for (int k = 0; k < 2; ++k) {
      int sb = sbp * 2 + k;
      float4 mv = *(const float4*)(M + (size_t)row * Sk + t * 64 + sb * 16 + quad * 4);
      o[k * 4 + 0] = f2bf(mv.x * SCALE_LOG2E);
      o[k * 4 + 1] = f2bf(mv.y * SCALE_LOG2E);
      o[k * 4 + 2] = f2bf(mv.z * SCALE_LOG2E);
      o[k * 4 + 3] = f2bf(mv.w * SCALE_LOG2E);
    }
    *(bf16x8*)(Mg + (size_t)u * 8) = *(const bf16x8*)o;
  }
}

template <int NS>
__global__ __launch_bounds__(256, 4) void attn_fwd(
    const float* __restrict__ Q, const short* __restrict__ KVf,
    const short* __restrict__ Mg, float* __restrict__ P0,
    float* __restrict__ P1, float* __restrict__ rsW)
{
  __shared__ short KV[2][8192];   // K+V fragment tile, double-buffered (2x16KB)

  const int tid  = threadIdx.x;
  const int lane = tid & 63;
  const int w    = tid >> 6;     // wave 0..3
  const int quad = lane >> 4;    // 0..3
  const int c    = lane & 15;    // 0..15

  // XCD-aware decode: XCD (id&7) hosts 4 nh values -> KV set 2.1MB fits L2.
  const int id   = blockIdx.x;
  const int slot = id >> 3;
  const int nh   = (id & 7) * 4 + (slot & 3);
  const int qt   = (slot >> 2) & 15;
  const int sp   = (NS == 2) ? (slot >> 6) : 0;
  const int n    = nh >> 4;
  const int h    = nh & 15;

  const int row0 = qt * BM + w * 32;   // wave's first global q row
  const int t0 = sp * (NT / NS), tc = NT / NS;

  // ---- Q fragments, pre-scaled (B-operand x32 layout), 2 q-rows per lane ----
  bf16x8 qfrag[2][2];   // [cb][kc]
#pragma unroll
  for (int cb = 0; cb < 2; ++cb) {
    const float* qp = Q + (((size_t)n * Lq + (row0 + cb * 16 + c)) * Hh + h) * Ee;
#pragma unroll
    for (int kc = 0; kc < 2; ++kc) {
      const float* p = qp + kc * 32 + quad * 8;
      float4 x = *(const float4*)(p);
      float4 y = *(const float4*)(p + 4);
      bf16x8 f;
      f[0] = f2bf(x.x * SCALE_LOG2E); f[1] = f2bf(x.y * SCALE_LOG2E);
      f[2] = f2bf(x.z * SCALE_LOG2E); f[3] = f2bf(x.w * SCALE_LOG2E);
      f[4] = f2bf(y.x * SCALE_LOG2E); f[5] = f2bf(y.y * SCALE_LOG2E);
      f[6] = f2bf(y.z * SCALE_LOG2E); f[7] = f2bf(y.w * SCALE_LOG2E);
      qfrag[cb][kc] = f;
    }
  }

  // O^T accumulator: o[cb][db][r] = O[q=row0+cb*16+c][d = db*16 + quad*4 + r]
  f32x4 o[2][4];
#pragma unroll
  for (int cb = 0; cb < 2; ++cb)
#pragma unroll
    for (int db = 0; db < 4; ++db) { o[cb][db][0] = 0.f; o[cb][db][1] = 0.f; o[cb][db][2] = 0.f; o[cb][db][3] = 0.f; }
  float rs[2] = {0.f, 0.f};

  const short* kvt = KVf + (size_t)nh * NT * 8192;
  // mask stream: 65536 shorts per (qt,w); 2048 per tile; 32 per lane
  const short* mbase = Mg + (size_t)(qt * 4 + w) * 65536 + lane * 32;

  // ---- prologue: async-stage KV tile t0; load mask frags for t0 ----
#pragma unroll
  for (int i = 0; i < 4; ++i) {
    int seg = w * 4 + i;
    async_copy16(kvt + ((size_t)t0 * 8192) + seg * 512 + lane * 8, &KV[0][seg * 512 + lane * 8]);
  }
  uint4v mcur[4], mnxt[4];
#pragma unroll
  for (int i = 0; i < 4; ++i) mcur[i] = *(const uint4v*)(mbase + (size_t)t0 * 2048 + i * 8);
  __syncthreads();

  for (int tt = 0; tt < tc; ++tt) {
    const int t = t0 + tt;
    const int buf = tt & 1;

    // ---- prefetch tile t+1: mask to regs, KV to LDS (async) ----
    if (tt + 1 < tc) {
      const short* gm = mbase + (size_t)(t + 1) * 2048;
#pragma unroll
      for (int i = 0; i < 4; ++i) mnxt[i] = *(const uint4v*)(gm + i * 8);
      const short* gk = kvt + (size_t)(t + 1) * 8192;
#pragma unroll
      for (int i = 0; i < 4; ++i) {
        int seg = w * 4 + i;
        async_copy16(gk + seg * 512 + lane * 8, &KV[buf ^ 1][seg * 512 + lane * 8]);
      }
    }

    const short* kb = &KV[buf][0];

    // ---- C-init from prefetched mask frags: sacc[cb][sb][r] = mask*SL at
    //      s = 16sb + 4quad + r, q = row0 + cb*16 + c ----
    f32x4 sacc[2][4];
#pragma unroll
    for (int cb = 0; cb < 2; ++cb)
#pragma unroll
      for (int sbp = 0; sbp < 2; ++sbp) {
        uint4v m = mcur[cb * 2 + sbp];
        sacc[cb][sbp * 2 + 0][0] = bf_lo(m.x); sacc[cb][sbp * 2 + 0][1] = bf_hi(m.x);
        sacc[cb][sbp * 2 + 0][2] = bf_lo(m.y); sacc[cb][sbp * 2 + 0][3] = bf_hi(m.y);
        sacc[cb][sbp * 2 + 1][0] = bf_lo(m.z); sacc[cb][sbp * 2 + 1][1] = bf_hi(m.z);
        sacc[cb][sbp * 2 + 1][2] = bf_lo(m.w); sacc[cb][sbp * 2 + 1][3] = bf_hi(m.w);
      }

    // ---- S^T = K Q^T (x32 MFMAs, K frags from LDS) ----
#pragma unroll
    for (int kc = 0; kc < 2; ++kc) {
#pragma unroll
      for (int sb = 0; sb < 4; ++sb) {
        bf16x8 kfrag = *(const bf16x8*)&kb[(sb * 2 + kc) * 512 + lane * 8];
#pragma unroll
        for (int cb = 0; cb < 2; ++cb)
          sacc[cb][sb] = __builtin_amdgcn_mfma_f32_16x16x32_bf16(kfrag, qfrag[cb][kc], sacc[cb][sb], 0, 0, 0);
      }
    }

    // ---- p = exp2(sacc), accumulate rs, pack straight into x16 B-frags ----
    short4v pv[2][4];
#pragma unroll
    for (int cb = 0; cb < 2; ++cb)
#pragma unroll
      for (int sb = 0; sb < 4; ++sb) {
        float p0 = __builtin_amdgcn_exp2f(sacc[cb][sb][0]);
        float p1 = __builtin_amdgcn_exp2f(sacc[cb][sb][1]);
        float p2 = __builtin_amdgcn_exp2f(sacc[cb][sb][2]);
        float p3 = __builtin_amdgcn_exp2f(sacc[cb][sb][3]);
        rs[cb] += (p0 + p1) + (p2 + p3);
        union { uint2v u; short4v s; } uu;
        uu.u.x = pack_bf16x2(p0, p1);
        uu.u.y = pack_bf16x2(p2, p3);
        pv[cb][sb] = uu.s;   // B[k=4quad+j][n=c] for s-block sb -- no LDS!
      }

    // ---- O^T += V^T P^T : x16 MFMAs, A = V frags (b64), B = pv registers ----
#pragma unroll
    for (int sb = 0; sb < 4; ++sb) {
#pragma unroll
      for (int db = 0; db < 4; ++db) {
        short4v vfrag = *(const short4v*)&kb[4096 + (db * 4 + sb) * 256 + lane * 4];
#pragma unroll
        for (int cb = 0; cb < 2; ++cb)
          o[cb][db] = __builtin_amdgcn_mfma_f32_16x16x16bf16_1k(vfrag, pv[cb][sb], o[cb][db], 0, 0, 0);
      }
    }

    __syncthreads();  // drains async t+1; protects buf reuse
#pragma unroll
    for (int i = 0; i < 4; ++i) mcur[i] = mnxt[i];
  }

  // ---- epilogue: write partial O and partial row-sums ----
  float* P = (sp == 0) ? P0 : P1;
#pragma unroll
  for (int cb = 0; cb < 2; ++cb) {
    float v = rs[cb];
    v += __shfl_xor(v, 16, 64);
    v += __shfl_xor(v, 32, 64);
    const int qrow = row0 + cb * 16 + c;
    if (quad == 0) rsW[(size_t)sp * 65536 + nh * 2048 + qrow] = v;
    float* op = P + (((size_t)n * Lq + qrow) * Hh + h) * Dd + quad * 4;
#pragma unroll
    for (int db = 0; db < 4; ++db) {
      float4 ov;
      ov.x = o[cb][db][0]; ov.y = o[cb][db][1];
      ov.z = o[cb][db][2]; ov.w = o[cb][db][3];
      *(float4*)(op + db * 16) = ov;
    }
  }
}

template <int NS>
__global__ __launch_bounds__(256) void combine(float* __restrict__ Out,
                                               const float* __restrict__ P1,
                                               const float* __restrict__ rsW) {
  int gid = blockIdx.x * 256 + threadIdx.x;
  size_t i4 = (size_t)gid * 4;
  int hh = (int)((i4 >> 6) & 15);
  int l  = (int)((i4 >> 10) & 2047);
  int nn = (int)(i4 >> 21);
  int nh = nn * 16 + hh;
  float rs = rsW[nh * 2048 + l];
  float4 v = *(const float4*)(Out + i4);
  if (NS == 2) {
    rs += rsW[65536 + (size_t)nh * 2048 + l];
    float4 b = *(const float4*)(P1 + i4);
    v.x += b.x; v.y += b.y; v.z += b.z; v.w += b.w;
  }
  float inv = 1.0f / rs;
  v.x *= inv; v.y *= inv; v.z *= inv; v.w *= inv;
  *(float4*)(Out + i4) = v;
}

extern "C" void kernel_launch(void* const* d_in, const int* in_sizes, int n_in,
                              void* d_out, int out_size, void* d_ws, size_t ws_size,
                              hipStream_t stream) {
  const float* Q   = (const float*)d_in[0];
  const float* K   = (const float*)d_in[1];
  const float* V   = (const float*)d_in[2];
  const float* Msk = (const float*)d_in[3];
  float* Out = (float*)d_out;

  short* KVf = (short*)d_ws;                         // 16.78 MB
  short* Mg  = KVf + (size_t)8388608;                // 8.39 MB
  float* rsW = (float*)(Mg + (size_t)4194304);       // 0.52 MB (2 splits)
  float* P1  = rsW + 131072;                         // 16.78 MB (split=2 only)

  const size_t need2 = 16777216u + 8388608u + 524288u + 16777216u;
  const bool split = ws_size >= need2;

  prep_all<<<dim3(KVB + MSKB), dim3(256), 0, stream>>>(K, V, Msk, KVf, Mg);

  if (split) {
    attn_fwd<2><<<dim3(1024), dim3(256), 0, stream>>>(Q, KVf, Mg, Out, P1, rsW);
    combine<2><<<dim3(4096), dim3(256), 0, stream>>>(Out, P1, rsW);
  } else {
    attn_fwd<1><<<dim3(512), dim3(256), 0, stream>>>(Q, KVf, Mg, Out, P1, rsW);
    combine<1><<<dim3(4096), dim3(256), 0, stream>>>(Out, P1, rsW);
  }
}